// Round 6
// baseline (655.840 us; speedup 1.0000x reference)
//
#include <hip/hip_runtime.h>
#include <math.h>

#define N_GRD 4
#define M_SAT 32
#define C_CH  32
#define HK    64
#define WK    64
#define HO    65
#define WO    65
#define SAMPLE_ELEMS (C_CH * HK * WK)

typedef _Float16 h8 __attribute__((ext_vector_type(8)));
typedef float    f4 __attribute__((ext_vector_type(4)));
typedef unsigned int u32;

// ---- ws layout (float units) ----
#define OFF_INV    0
#define OFF_S      64                 // 32 * 4225
#define OFF_CANDV  135264
#define OFF_CANDI  135776
#define OFF_PART   136288
#define PART_FLOATS 6553600           // 8 slices * 32 m * 4 n * 80 xslot * 80 y
#define OFF_G2F    (OFF_PART + PART_FLOATS)
#define G2_HALFS   1736704            // 2cp * 8cq * 64i * 4n * 106js * 4c

#define G2_BLOCKS  6784               // ceil(G2_HALFS/256)
#define PREP_BLOCKS (G2_BLOCKS + M_SAT + N_GRD)

// ---------------------------------------------------------------------------
// K1 (fused prep): bx<6784 -> g2 Toeplitz build; next 32 -> per-m SAT of
// s2=sum_c sat^2 (+ sat inv-norm, free from last prefix entry); last 4 ->
// grd inv-norms.
// g2 layout [cp2][cq8][i64][n4][js106][c4]; value at js = g[n][cq*4+c][i][j],
// j = js-16-cp (zero outside [0,64)).  Parity copies keep shifted 16B reads
// aligned (js0 parity == cp by construction).
// ---------------------------------------------------------------------------
__global__ __launch_bounds__(256) void prep_kernel(const float* __restrict__ grd,
                                                   const float* __restrict__ sat,
                                                   _Float16* __restrict__ g2,
                                                   float* __restrict__ S,
                                                   float* __restrict__ inv) {
    const int bx = blockIdx.x;
    const int tid = threadIdx.x;
    __shared__ float s2[64][65];

    if (bx < G2_BLOCKS) {
        int idx = bx * 256 + tid;
        if (idx < G2_HALFS) {
            int c = idx & 3; int t = idx >> 2;
            int js = t % 106; t /= 106;
            int n = t & 3; t >>= 2;
            int i = t & 63; t >>= 6;
            int cq = t & 7; int cp = t >> 3;
            int j = js - 16 - cp;
            float v = 0.0f;
            if (j >= 0 && j < 64)
                v = grd[(((size_t)n * 32 + (cq * 4 + c)) * 64 + i) * 64 + j];
            g2[idx] = (_Float16)v;
        }
        return;
    }
    if (bx < G2_BLOCKS + M_SAT) {
        const int m = bx - G2_BLOCKS;
        const float* base = sat + (size_t)m * SAMPLE_ELEMS;
        for (int p = tid; p < HK * WK; p += 256) {
            float s = 0.0f;
            for (int c = 0; c < C_CH; ++c) {
                float v = base[c * (HK * WK) + p];
                s += v * v;
            }
            s2[p >> 6][p & 63] = s;
        }
        __syncthreads();
        if (tid < 64) {
            int r = tid; float run = 0.0f;
            for (int w = 0; w < 64; ++w) { run += s2[r][w]; s2[r][w] = run; }
        }
        __syncthreads();
        if (tid < 64) {
            int c = tid; float run = 0.0f;
            for (int h = 0; h < 64; ++h) { run += s2[h][c]; s2[h][c] = run; }
        }
        __syncthreads();
        if (tid == 0)
            inv[N_GRD + m] = 1.0f / fmaxf(sqrtf(s2[63][63]), 1e-12f);
        float* Sm = S + (size_t)m * (HO * WO);
        for (int p = tid; p < HO * WO; p += 256) {
            int r = p / 65, c = p - r * 65;
            Sm[p] = (r == 0 || c == 0) ? 0.0f : s2[r - 1][c - 1];
        }
        return;
    }
    {   // grd norms
        const int b = bx - G2_BLOCKS - M_SAT;
        const float4* v = reinterpret_cast<const float4*>(grd + (size_t)b * SAMPLE_ELEMS);
        float ss = 0.0f;
        for (int p = tid; p < SAMPLE_ELEMS / 4; p += 256) {
            float4 q = v[p];
            ss += q.x * q.x + q.y * q.y + q.z * q.z + q.w * q.w;
        }
        for (int off = 32; off > 0; off >>= 1) ss += __shfl_down(ss, off);
        __shared__ float ls[4];
        int lane = tid & 63, w = tid >> 6;
        if (lane == 0) ls[w] = ss;
        __syncthreads();
        if (tid == 0)
            inv[b] = 1.0f / fmaxf(sqrtf(ls[0] + ls[1] + ls[2] + ls[3]), 1e-12f);
    }
}

// ---------------------------------------------------------------------------
// K2: MFMA correlation, B read DIRECTLY from global (L1/L2-hot g2) — no B
// LDS staging, no per-ii barriers.  Grid (m=32, xs=5, z=8: h=z&1, qt=z>>1).
// 4 waves split i.  Per wave: 5 y-tiles (t=4 row0 == y64; rows 1..15 read
// in-LDS garbage, discarded) x 4 n.  xs=4 covers x=49..64 (overlap waste).
// A LDS pad +5376 B keeps t=4 garbage rows in-bounds.
// partial[slice8][m][n][xslot80][y80], xslot = xs*16+ss, yin = t*16+row.
// ---------------------------------------------------------------------------
__global__ __launch_bounds__(256, 2) void corr_mfma_kernel(const float* __restrict__ sat,
                                                           const _Float16* __restrict__ g2,
                                                           float* __restrict__ partial) {
    __shared__ __align__(16) char lds[48384];   // 43008 A + 5376 garbage pad
    char* AB = lds;

    const int m  = blockIdx.x;
    const int xs = blockIdx.y;
    const int z  = blockIdx.z;
    const int h  = z & 1;
    const int qt = z >> 1;

    const int x00 = (xs < 4) ? 16 * xs : 49;
    const int qb  = (xs < 4) ? 16 * xs : 48;
    const int xoff = x00 - qb;
    const int qstage = qb + 40 * h;

    const int tid  = threadIdx.x;
    const int w    = tid >> 6;
    const int lane = tid & 63;
    const int s    = lane & 15;
    const int u    = lane >> 4;
    const int cp   = (s + xoff) & 1;

    f4 acc[5][4];
#pragma unroll
    for (int t = 0; t < 5; ++t)
#pragma unroll
        for (int n = 0; n < 4; ++n) { acc[t][n][0]=0.f; acc[t][n][1]=0.f; acc[t][n][2]=0.f; acc[t][n][3]=0.f; }

    // per-lane global B base: byte(cp,cq,i,n,js) = ((cp*8+cq)*64+i)*3392 + n*848 + js*8
    const int js0 = 16 + cp + 40 * h + 2 * u - s - xoff;   // >= 0; parity == cp
    const char* bp0 = (const char*)g2 + (size_t)cp * 1736704
                      + (size_t)(qt * 2) * 217088 + (w * 16) * 3392 + js0 * 8;

    const int abase0 = s * 336 + u * 16;

    for (int cqi = 0; cqi < 2; ++cqi) {
        const int cq = qt * 2 + cqi;
        __syncthreads();  // prior readers of AB done
        // ---- stage A: 128 padded rows x 21 granules (g==20 stride pad)
        for (int k = 0; k < 11; ++k) {
            int idx = k * 256 + tid;
            if (idx < 2688) {
                int r = idx / 21;
                int g = idx - r * 21;
                int q = qstage + 2 * g;
                h8 hv = {0, 0, 0, 0, 0, 0, 0, 0};
                if (g < 20 && r >= 32 && r < 96 && q >= 32 && q < 96) {
                    const float* sp = sat + (((size_t)(m * 32 + cq * 4)) * 64 + (r - 32)) * 64 + (q - 32);
                    float2 v0 = *(const float2*)(sp);
                    float2 v1 = *(const float2*)(sp + 4096);
                    float2 v2 = *(const float2*)(sp + 8192);
                    float2 v3 = *(const float2*)(sp + 12288);
                    hv[0] = (_Float16)v0.x; hv[1] = (_Float16)v1.x; hv[2] = (_Float16)v2.x; hv[3] = (_Float16)v3.x;
                    hv[4] = (_Float16)v0.y; hv[5] = (_Float16)v1.y; hv[6] = (_Float16)v2.y; hv[7] = (_Float16)v3.y;
                }
                *(h8*)(AB + idx * 16) = hv;
            }
        }
        __syncthreads();  // A ready
        const char* bpc = bp0 + cqi * 217088;
        for (int ii = 0; ii < 16; ++ii) {
            const char* Ab = AB + abase0 + (w * 16 + ii) * 336;
            const char* Bb = bpc + ii * 3392;
#pragma unroll
            for (int qs = 0; qs < 5; ++qs) {
                h8 a[5]; h8 bfr[4];
#pragma unroll
                for (int n = 0; n < 4; ++n) bfr[n] = *(const h8*)(Bb + n * 848 + qs * 64);
#pragma unroll
                for (int t = 0; t < 5; ++t) a[t] = *(const h8*)(Ab + qs * 64 + t * 5376);
#pragma unroll
                for (int t = 0; t < 5; ++t)
#pragma unroll
                    for (int n = 0; n < 4; ++n)
                        acc[t][n] = __builtin_amdgcn_mfma_f32_16x16x32_f16(a[t], bfr[n], acc[t][n], 0, 0, 0);
            }
        }
    }

    // ---- cross-wave (i) reduce in LDS; store coalesced-friendly layout
    float* red = (float*)lds;
    const int pbase = (((h * 4 + qt) * 32 + m) * 4) * 6400;
#pragma unroll
    for (int t = 0; t < 5; ++t) {
        __syncthreads();
#pragma unroll
        for (int nn = 0; nn < 4; ++nn)
            *(f4*)(red + ((nn * 4 + w) * 64 + lane) * 4) = acc[t][nn];
        __syncthreads();
        {
            int nn = tid >> 6, ln = tid & 63;
            f4 sum = *(f4*)(red + ((nn * 4 + 0) * 64 + ln) * 4);
            sum = sum + *(f4*)(red + ((nn * 4 + 1) * 64 + ln) * 4);
            sum = sum + *(f4*)(red + ((nn * 4 + 2) * 64 + ln) * 4);
            sum = sum + *(f4*)(red + ((nn * 4 + 3) * 64 + ln) * 4);
            int ss = ln & 15, uu = ln >> 4;
            int xsl = xs * 16 + ss;
            int yin = t * 16 + uu * 4;
            *(f4*)(partial + pbase + nn * 6400 + xsl * 80 + yin) = sum;
        }
    }
}

// ---------------------------------------------------------------------------
// K3: reduce 8 slices + normalize + top-4 candidates per (m,n).
// Coalesced: loop pp = x*65+y (y stride-1 matches partial layout).
// ---------------------------------------------------------------------------
__global__ __launch_bounds__(256) void epilogue_kernel(const float* __restrict__ partial,
                                                       const float* __restrict__ S,
                                                       const float* __restrict__ inv,
                                                       const int* __restrict__ unc,
                                                       float* __restrict__ candv,
                                                       int* __restrict__ candi) {
    const int b = blockIdx.x;
    const int m = b >> 2, n = b & 3;
    const int tid = threadIdx.x;
    const float uu = (float)unc[0];
    const float sc = inv[n] * inv[N_GRD + m];
    const float isn = inv[N_GRD + m];
    const float* Sm = S + (size_t)m * 4225;
    const float* pb = partial + (size_t)(m * 4 + n) * 6400;

    float best = -3.4e38f;
    int bidx = 0x7fffffff;
    for (int pp = tid; pp < 4225; pp += 256) {
        int x = pp / 65, y = pp - x * 65;
        int xsl = (x == 64) ? 79 : x;
        int so = xsl * 80 + y;
        float raw = 0.0f;
#pragma unroll
        for (int sl = 0; sl < 8; ++sl) raw += pb[(size_t)sl * 819200 + so];
        float num = raw * sc;
        int r0 = max(0, y - 32), r1 = min(64, y + 32);
        int q0 = max(0, x - 32), q1 = min(64, x + 32);
        float ps = Sm[r1 * 65 + q1] - Sm[r0 * 65 + q1] - Sm[r1 * 65 + q0] + Sm[r0 * 65 + q0];
        float denom = fmaxf(sqrtf(ps) * isn * uu, 1e-12f);
        float v = num / denom;
        int p = y * 65 + x;
        if (v > best || (v == best && p < bidx)) { best = v; bidx = p; }
    }
    __shared__ float bv[256]; __shared__ int bi[256];
    __shared__ float cv[256]; __shared__ int ci[256];
    __shared__ int winner;
    bv[tid] = best; bi[tid] = bidx;
    __syncthreads();
    for (int round = 0; round < 4; ++round) {
        cv[tid] = bv[tid]; ci[tid] = bi[tid];
        __syncthreads();
        for (int st = 128; st > 0; st >>= 1) {
            if (tid < st) {
                float ov = cv[tid + st]; int oi = ci[tid + st];
                if (ov > cv[tid] || (ov == cv[tid] && oi < ci[tid])) { cv[tid] = ov; ci[tid] = oi; }
            }
            __syncthreads();
        }
        if (tid == 0) { candv[b * 4 + round] = cv[0]; candi[b * 4 + round] = ci[0]; winner = ci[0]; }
        __syncthreads();
        if (bi[tid] == winner) bv[tid] = -3.4e38f;
        __syncthreads();
    }
}

// ---------------------------------------------------------------------------
// K4: refine (merged dots + pick).  128 blocks; each recomputes its active
// candidates (top-1 + any within fp16-noise margin) exactly in fp32, picks
// the max with first-index tie-break, writes both outputs.
// ---------------------------------------------------------------------------
__global__ __launch_bounds__(256) void refine_kernel(const float* __restrict__ grd,
                                                     const float* __restrict__ sat,
                                                     const float* __restrict__ S,
                                                     const float* __restrict__ inv,
                                                     const int* __restrict__ unc,
                                                     const float* __restrict__ candv,
                                                     const int* __restrict__ candi,
                                                     float* __restrict__ out) {
    const int b = blockIdx.x;
    const int m = b >> 2, n = b & 3;
    const int tid = threadIdx.x, lane = tid & 63, w = tid >> 6;
    const float uu = (float)unc[0];
    const float sc = inv[n] * inv[N_GRD + m];
    const float isn = inv[N_GRD + m];
    const float* Sm = S + (size_t)m * 4225;

    float v0 = candv[b * 4];
    float thr = v0 - (0.02f * fabsf(v0) + 1e-4f);
    int K = 1;
    if (candv[b * 4 + 1] >= thr) { K = 2;
        if (candv[b * 4 + 2] >= thr) { K = 3;
            if (candv[b * 4 + 3] >= thr) K = 4; } }

    __shared__ float ls[4];
    float bestv = -3.4e38f; int bestp = 0x7fffffff;
    for (int k = 0; k < K; ++k) {
        int p = candi[b * 4 + k];
        int y = p / 65, x = p - y * 65;
        const int ilo = max(0, 32 - y), ihi = min(64, 96 - y);
        int xj = x + lane - 32;
        float acc = 0.0f;
        if (xj >= 0 && xj < 64) {
            const float* sm = sat + (size_t)m * SAMPLE_ELEMS;
            const float* gn = grd + (size_t)n * SAMPLE_ELEMS;
            for (int c = 0; c < 32; ++c) {
                const int cbase = c << 12;
                const float* sp = sm + cbase + xj + ((y - 32) << 6);
                const float* gp = gn + cbase + lane;
                for (int i = ilo + w; i < ihi; i += 4)
                    acc = fmaf(sp[i << 6], gp[i << 6], acc);
            }
        }
        for (int off = 32; off > 0; off >>= 1) acc += __shfl_down(acc, off);
        if (lane == 0) ls[w] = acc;
        __syncthreads();
        if (tid == 0) {
            float dot = ls[0] + ls[1] + ls[2] + ls[3];
            int r0 = max(0, y - 32), r1 = min(64, y + 32);
            int q0 = max(0, x - 32), q1 = min(64, x + 32);
            float ps = Sm[r1 * 65 + q1] - Sm[r0 * 65 + q1] - Sm[r1 * 65 + q0] + Sm[r0 * 65 + q0];
            float denom = fmaxf(sqrtf(ps) * isn * uu, 1e-12f);
            float v = dot * sc / denom;
            if (v > bestv || (v == bestv && p < bestp)) { bestv = v; bestp = p; }
        }
        __syncthreads();
    }
    if (tid == 0) {
        out[b] = bestv;
        int row = bestp / 65, col = bestp - row * 65;
        float pr = -((float)row - 32.5f);
        float pc = (float)col - 32.5f;
        out[128 + b * 2 + 0] = ((pr * 0.2f) * 512.0f) * (1.0f / 128.0f);
        out[128 + b * 2 + 1] = ((pc * 0.2f) * 512.0f) * (1.0f / 128.0f);
    }
}

// ---------------------------------------------------------------------------
extern "C" void kernel_launch(void* const* d_in, const int* in_sizes, int n_in,
                              void* d_out, int out_size, void* d_ws, size_t ws_size,
                              hipStream_t stream) {
    const float* grd = (const float*)d_in[0];
    const float* sat = (const float*)d_in[1];
    const int*   unc = (const int*)d_in[2];
    float* out = (float*)d_out;
    float* ws  = (float*)d_ws;

    float* inv     = ws + OFF_INV;
    float* S       = ws + OFF_S;
    float* candv   = ws + OFF_CANDV;
    int*   candi   = (int*)(ws + OFF_CANDI);
    float* partial = ws + OFF_PART;
    _Float16* g2   = (_Float16*)(ws + OFF_G2F);   // ~30.2 MB total ws use

    prep_kernel<<<PREP_BLOCKS, 256, 0, stream>>>(grd, sat, g2, S, inv);
    corr_mfma_kernel<<<dim3(M_SAT, 5, 8), 256, 0, stream>>>(sat, g2, partial);
    epilogue_kernel<<<M_SAT * N_GRD, 256, 0, stream>>>(partial, S, inv, unc, candv, candi);
    refine_kernel<<<M_SAT * N_GRD, 256, 0, stream>>>(grd, sat, S, inv, unc, candv, candi, out);
}

// Round 7
// 375.686 us; speedup vs baseline: 1.7457x; 1.7457x over previous
//
#include <hip/hip_runtime.h>
#include <math.h>

#define N_GRD 4
#define M_SAT 32
#define C_CH  32
#define HK    64
#define WK    64
#define HO    65
#define WO    65
#define SAMPLE_ELEMS (C_CH * HK * WK)

typedef _Float16 h8 __attribute__((ext_vector_type(8)));
typedef float    f4 __attribute__((ext_vector_type(4)));
typedef unsigned int u32;

// ---- ws layout (float units) ----
#define OFF_INV    0
#define OFF_S      64                 // 32 * 4225
#define OFF_CANDV  135264
#define OFF_CANDI  135776
#define OFF_DOTS   136288             // 512
#define OFF_PART   136800             // 32 m * 4 n * 80 xsl * 80 y = 819200
#define OFF_G2F    956000             // G2_HALFS/2 floats
#define OFF_SH     1824352            // 524288 granules * 8 halfs = 2097152 floats
#define G2_HALFS   1736704            // 2cp * 8cq * 64i * 4n * 106js * 4c

#define G2_BLOCKS  6784               // G2_HALFS/256
#define SH_BLOCKS  2048               // 524288/256
#define PREP_BLOCKS (G2_BLOCKS + SH_BLOCKS + M_SAT + N_GRD)

// ---------------------------------------------------------------------------
// K1 (fused prep), by blockIdx range:
//  [0,6784)        g2 Toeplitz build (fp16 grd, parity copies for alignment)
//  [6784,8832)     sh build: fp16 sat in DMA-granule layout
//                  sh[m][cq][r64][gr32] granule = 8 halfs [q2][c4],
//                  value = sat[m][cq*4+c][r][2*gr+q2]
//  [8832,8864)     per-m SAT of s2 (+ sat inv-norm)
//  [8864,8868)     grd inv-norms
// ---------------------------------------------------------------------------
__global__ __launch_bounds__(256) void prep_kernel(const float* __restrict__ grd,
                                                   const float* __restrict__ sat,
                                                   _Float16* __restrict__ g2,
                                                   _Float16* __restrict__ sh,
                                                   float* __restrict__ S,
                                                   float* __restrict__ inv) {
    const int bx = blockIdx.x;
    const int tid = threadIdx.x;
    __shared__ float s2[64][65];

    if (bx < G2_BLOCKS) {
        int idx = bx * 256 + tid;
        int c = idx & 3; int t = idx >> 2;
        int js = t % 106; t /= 106;
        int n = t & 3; t >>= 2;
        int i = t & 63; t >>= 6;
        int cq = t & 7; int cp = t >> 3;
        int j = js - 16 - cp;
        float v = 0.0f;
        if (j >= 0 && j < 64)
            v = grd[(((size_t)n * 32 + (cq * 4 + c)) * 64 + i) * 64 + j];
        g2[idx] = (_Float16)v;
        return;
    }
    if (bx < G2_BLOCKS + SH_BLOCKS) {
        int idx = (bx - G2_BLOCKS) * 256 + tid;    // granule index < 524288
        int gr = idx & 31;
        int r  = (idx >> 5) & 63;
        int cq = (idx >> 11) & 7;
        int mm = idx >> 14;
        const float* sp = sat + (((size_t)mm * 32 + cq * 4) * 64 + r) * 64 + gr * 2;
        float2 v0 = *(const float2*)(sp);
        float2 v1 = *(const float2*)(sp + 4096);
        float2 v2 = *(const float2*)(sp + 8192);
        float2 v3 = *(const float2*)(sp + 12288);
        h8 hv = {(_Float16)v0.x, (_Float16)v1.x, (_Float16)v2.x, (_Float16)v3.x,
                 (_Float16)v0.y, (_Float16)v1.y, (_Float16)v2.y, (_Float16)v3.y};
        *(h8*)(sh + (size_t)idx * 8) = hv;
        return;
    }
    if (bx < G2_BLOCKS + SH_BLOCKS + M_SAT) {
        const int m = bx - G2_BLOCKS - SH_BLOCKS;
        const float* base = sat + (size_t)m * SAMPLE_ELEMS;
        for (int p = tid; p < HK * WK; p += 256) {
            float s = 0.0f;
            for (int c = 0; c < C_CH; ++c) {
                float v = base[c * (HK * WK) + p];
                s += v * v;
            }
            s2[p >> 6][p & 63] = s;
        }
        __syncthreads();
        if (tid < 64) {
            int r = tid; float run = 0.0f;
            for (int w = 0; w < 64; ++w) { run += s2[r][w]; s2[r][w] = run; }
        }
        __syncthreads();
        if (tid < 64) {
            int c = tid; float run = 0.0f;
            for (int h = 0; h < 64; ++h) { run += s2[h][c]; s2[h][c] = run; }
        }
        __syncthreads();
        if (tid == 0)
            inv[N_GRD + m] = 1.0f / fmaxf(sqrtf(s2[63][63]), 1e-12f);
        float* Sm = S + (size_t)m * (HO * WO);
        for (int p = tid; p < HO * WO; p += 256) {
            int r = p / 65, c = p - r * 65;
            Sm[p] = (r == 0 || c == 0) ? 0.0f : s2[r - 1][c - 1];
        }
        return;
    }
    {   // grd norms
        const int b = bx - G2_BLOCKS - SH_BLOCKS - M_SAT;
        const float4* v = reinterpret_cast<const float4*>(grd + (size_t)b * SAMPLE_ELEMS);
        float ss = 0.0f;
        for (int p = tid; p < SAMPLE_ELEMS / 4; p += 256) {
            float4 q = v[p];
            ss += q.x * q.x + q.y * q.y + q.z * q.z + q.w * q.w;
        }
        for (int off = 32; off > 0; off >>= 1) ss += __shfl_down(ss, off);
        __shared__ float ls[4];
        int lane = tid & 63, w = tid >> 6;
        if (lane == 0) ls[w] = ss;
        __syncthreads();
        if (tid == 0)
            inv[b] = 1.0f / fmaxf(sqrtf(ls[0] + ls[1] + ls[2] + ls[3]), 1e-12f);
    }
}

// ---------------------------------------------------------------------------
// K2: MFMA correlation.  Grid (m=32, xs=5, z=8: h=z&1, qt=z>>1); 4 waves = i.
// A staged per cqi via global_load_lds(16) from sh (zero-redirect implements
// padding + the 21st stride-pad granule).  B staged per ii via
// global_load_lds(16) from g2 (R4 structure, measured-good).
// 5 y-tiles (t=4 row0 == y64, rows 1..15 garbage) x 4 n; xs=4 covers x=49..64.
// Output: fp32 atomicAdd into partial[m][n][xsl80][y80] (memset before).
// ---------------------------------------------------------------------------
__global__ __launch_bounds__(256, 2) void corr_mfma_kernel(const _Float16* __restrict__ sh,
                                                           const _Float16* __restrict__ g2,
                                                           float* __restrict__ partial) {
    __shared__ __align__(16) char lds[75520];   // 43008 A + 5376 pad + 27136 B
    char* AB = lds;
    char* BB = lds + 48384;

    const int m  = blockIdx.x;
    const int xs = blockIdx.y;
    const int z  = blockIdx.z;
    const int h  = z & 1;
    const int qt = z >> 1;

    const int x00 = (xs < 4) ? 16 * xs : 49;
    const int qb  = (xs < 4) ? 16 * xs : 48;
    const int xoff = x00 - qb;
    const int qstage = qb + 40 * h;

    const int tid  = threadIdx.x;
    const int w    = tid >> 6;
    const int lane = tid & 63;
    const int s    = lane & 15;
    const int u    = lane >> 4;
    const int cp   = (s + xoff) & 1;

    f4 acc[5][4];
#pragma unroll
    for (int t = 0; t < 5; ++t)
#pragma unroll
        for (int n = 0; n < 4; ++n) { acc[t][n][0]=0.f; acc[t][n][1]=0.f; acc[t][n][2]=0.f; acc[t][n][3]=0.f; }

    const int bbase = ((w * 2 + cp) * 4 * 106 + (16 + cp + 40 * h + 2 * u - s - xoff)) * 8;
    const int abase0 = s * 336 + u * 16;
    const int q2base = qstage >> 1;

    for (int cqi = 0; cqi < 2; ++cqi) {
        const int cq = qt * 2 + cqi;
        __syncthreads();  // prior readers of AB done
        // ---- stage A via DMA: 2688 granules (+ tail into pad region)
        for (int k = 0; k < 11; ++k) {
            int idx = k * 256 + tid;
            if (idx < 2688) {
                u32 r = (u32)idx / 21u;
                u32 g = (u32)idx - r * 21u;
                int q2 = q2base + (int)g;
                bool valid = (g < 20u) & (r >= 32u) & (r < 96u) & (q2 >= 16) & (q2 < 48);
                const _Float16* src = valid
                    ? sh + ((((size_t)m * 8 + cq) * 64 + (r - 32)) * 32 + (q2 - 16)) * 8
                    : g2;   // first granules of g2 are structurally zero
                __builtin_amdgcn_global_load_lds(
                    (const __attribute__((address_space(1))) u32*)(const void*)src,
                    (__attribute__((address_space(3))) u32*)(void*)(AB + k * 4096 + w * 1024),
                    16, 0, 0);
            }
        }
        for (int ii = 0; ii < 16; ++ii) {
            __syncthreads();  // A/B ready for prior step done; drains DMA
            // ---- stage B via DMA: 1696 granules for this ii
            for (int k = 0; k < 7; ++k) {
                int idx = k * 256 + tid;
                if (idx < 1696) {
                    int wi = idx / 424;  int rm  = idx - wi * 424;
                    int cpp = rm / 212;  int rm2 = rm - cpp * 212;
                    int nn = rm2 / 53;   int jg  = rm2 - nn * 53;
                    int iw = wi * 16 + ii;
                    const _Float16* gsrc = g2 + (size_t)((((cpp * 8 + cq) * 64 + iw) * 4 + nn)) * 424 + jg * 8;
                    __builtin_amdgcn_global_load_lds(
                        (const __attribute__((address_space(1))) u32*)(const void*)gsrc,
                        (__attribute__((address_space(3))) u32*)(void*)(BB + k * 4096 + w * 1024),
                        16, 0, 0);
                }
            }
            __syncthreads();  // B ready (barrier drains vmcnt)
            const char* Ab = AB + abase0 + (w * 16 + ii) * 336;
            const char* Bb = BB + bbase;
#pragma unroll
            for (int qs = 0; qs < 5; ++qs) {
                h8 a[5]; h8 bfr[4];
#pragma unroll
                for (int n = 0; n < 4; ++n) bfr[n] = *(const h8*)(Bb + qs * 64 + n * 848);
#pragma unroll
                for (int t = 0; t < 5; ++t) a[t] = *(const h8*)(Ab + qs * 64 + t * 5376);
#pragma unroll
                for (int t = 0; t < 5; ++t)
#pragma unroll
                    for (int n = 0; n < 4; ++n)
                        acc[t][n] = __builtin_amdgcn_mfma_f32_16x16x32_f16(a[t], bfr[n], acc[t][n], 0, 0, 0);
            }
        }
    }

    // ---- cross-wave (i) reduce in LDS, then atomicAdd into partial
    float* red = (float*)lds;
#pragma unroll
    for (int t = 0; t < 5; ++t) {
        __syncthreads();
#pragma unroll
        for (int nn = 0; nn < 4; ++nn)
            *(f4*)(red + ((nn * 4 + w) * 64 + lane) * 4) = acc[t][nn];
        __syncthreads();
        {
            int nn = tid >> 6, ln = tid & 63;
            f4 sum = *(f4*)(red + ((nn * 4 + 0) * 64 + ln) * 4);
            sum = sum + *(f4*)(red + ((nn * 4 + 1) * 64 + ln) * 4);
            sum = sum + *(f4*)(red + ((nn * 4 + 2) * 64 + ln) * 4);
            sum = sum + *(f4*)(red + ((nn * 4 + 3) * 64 + ln) * 4);
            int ss = ln & 15, uu = ln >> 4;
            float* dst = partial + ((size_t)(m * 4 + nn)) * 6400
                         + (xs * 16 + ss) * 80 + t * 16 + uu * 4;
#pragma unroll
            for (int l = 0; l < 4; ++l) atomicAdd(dst + l, sum[l]);
        }
    }
}

// ---------------------------------------------------------------------------
// K3: normalize + top-4 candidates per (m,n).  Coalesced reads (y stride-1).
// ---------------------------------------------------------------------------
__global__ __launch_bounds__(256) void epilogue_kernel(const float* __restrict__ partial,
                                                       const float* __restrict__ S,
                                                       const float* __restrict__ inv,
                                                       const int* __restrict__ unc,
                                                       float* __restrict__ candv,
                                                       int* __restrict__ candi) {
    const int b = blockIdx.x;
    const int m = b >> 2, n = b & 3;
    const int tid = threadIdx.x;
    const float uu = (float)unc[0];
    const float sc = inv[n] * inv[N_GRD + m];
    const float isn = inv[N_GRD + m];
    const float* Sm = S + (size_t)m * 4225;
    const float* pb = partial + (size_t)(m * 4 + n) * 6400;

    float best = -3.4e38f;
    int bidx = 0x7fffffff;
    for (int pp = tid; pp < 4225; pp += 256) {
        int x = pp / 65, y = pp - x * 65;
        int xsl = (x == 64) ? 79 : x;
        float raw = pb[xsl * 80 + y];
        float num = raw * sc;
        int r0 = max(0, y - 32), r1 = min(64, y + 32);
        int q0 = max(0, x - 32), q1 = min(64, x + 32);
        float ps = Sm[r1 * 65 + q1] - Sm[r0 * 65 + q1] - Sm[r1 * 65 + q0] + Sm[r0 * 65 + q0];
        float denom = fmaxf(sqrtf(ps) * isn * uu, 1e-12f);
        float v = num / denom;
        int p = y * 65 + x;
        if (v > best || (v == best && p < bidx)) { best = v; bidx = p; }
    }
    __shared__ float bv[256]; __shared__ int bi[256];
    __shared__ float cv[256]; __shared__ int ci[256];
    __shared__ int winner;
    bv[tid] = best; bi[tid] = bidx;
    __syncthreads();
    for (int round = 0; round < 4; ++round) {
        cv[tid] = bv[tid]; ci[tid] = bi[tid];
        __syncthreads();
        for (int st = 128; st > 0; st >>= 1) {
            if (tid < st) {
                float ov = cv[tid + st]; int oi = ci[tid + st];
                if (ov > cv[tid] || (ov == cv[tid] && oi < ci[tid])) { cv[tid] = ov; ci[tid] = oi; }
            }
            __syncthreads();
        }
        if (tid == 0) { candv[b * 4 + round] = cv[0]; candi[b * 4 + round] = ci[0]; winner = ci[0]; }
        __syncthreads();
        if (bi[tid] == winner) bv[tid] = -3.4e38f;
        __syncthreads();
    }
}

// ---------------------------------------------------------------------------
// K4a: exact fp32 dot for candidate (b,k), split over 8 c-chunks (grid z).
// atomicAdd partial dots (dots memset to 0 before).
// ---------------------------------------------------------------------------
__global__ __launch_bounds__(256) void refine_dot_kernel(const float* __restrict__ grd,
                                                         const float* __restrict__ sat,
                                                         const float* __restrict__ candv,
                                                         const int* __restrict__ candi,
                                                         float* __restrict__ dots) {
    const int b = blockIdx.x;
    const int k = blockIdx.y;
    const int cq = blockIdx.z;
    const int m = b >> 2, n = b & 3;
    float v0 = candv[b * 4];
    float thr = v0 - (0.02f * fabsf(v0) + 1e-4f);
    if (k > 0 && candv[b * 4 + k] < thr) return;   // dots stays 0 (memset)
    int p = candi[b * 4 + k];
    int y = p / 65, x = p - y * 65;
    const int tid = threadIdx.x, lane = tid & 63, w = tid >> 6;
    const int ilo = max(0, 32 - y), ihi = min(64, 96 - y);
    int xj = x + lane - 32;
    float acc = 0.0f;
    if (xj >= 0 && xj < 64) {
        const float* sm = sat + (size_t)m * SAMPLE_ELEMS;
        const float* gn = grd + (size_t)n * SAMPLE_ELEMS;
        for (int cc = 0; cc < 4; ++cc) {
            const int cbase = (cq * 4 + cc) << 12;
            const float* sp = sm + cbase + xj + ((y - 32) << 6);
            const float* gp = gn + cbase + lane;
            for (int i = ilo + w; i < ihi; i += 4)
                acc = fmaf(sp[i << 6], gp[i << 6], acc);
        }
    }
    for (int off = 32; off > 0; off >>= 1) acc += __shfl_down(acc, off);
    __shared__ float ls[4];
    if (lane == 0) ls[w] = acc;
    __syncthreads();
    if (tid == 0) atomicAdd(&dots[b * 4 + k], ls[0] + ls[1] + ls[2] + ls[3]);
}

// ---------------------------------------------------------------------------
// K4b: pick best refined candidate per (m,n), write outputs.  1 block.
// ---------------------------------------------------------------------------
__global__ __launch_bounds__(128) void refine_pick_kernel(const float* __restrict__ S,
                                                          const float* __restrict__ inv,
                                                          const int* __restrict__ unc,
                                                          const float* __restrict__ candv,
                                                          const int* __restrict__ candi,
                                                          const float* __restrict__ dots,
                                                          float* __restrict__ out) {
    int b = threadIdx.x;
    if (b >= 128) return;
    const int m = b >> 2, n = b & 3;
    const float uu = (float)unc[0];
    const float sc = inv[n] * inv[N_GRD + m];
    const float isn = inv[N_GRD + m];
    const float* Sm = S + (size_t)m * 4225;
    float v0 = candv[b * 4];
    float thr = v0 - (0.02f * fabsf(v0) + 1e-4f);
    float bestv = -3.4e38f; int bestp = 0x7fffffff;
    for (int k = 0; k < 4; ++k) {
        if (k > 0 && candv[b * 4 + k] < thr) break;   // candv sorted desc
        int p = candi[b * 4 + k];
        int y = p / 65, x = p - y * 65;
        int r0 = max(0, y - 32), r1 = min(64, y + 32);
        int q0 = max(0, x - 32), q1 = min(64, x + 32);
        float ps = Sm[r1 * 65 + q1] - Sm[r0 * 65 + q1] - Sm[r1 * 65 + q0] + Sm[r0 * 65 + q0];
        float denom = fmaxf(sqrtf(ps) * isn * uu, 1e-12f);
        float v = dots[b * 4 + k] * sc / denom;
        if (v > bestv || (v == bestv && p < bestp)) { bestv = v; bestp = p; }
    }
    out[b] = bestv;
    int row = bestp / 65, col = bestp - row * 65;
    float pr = -((float)row - 32.5f);
    float pc = (float)col - 32.5f;
    out[128 + b * 2 + 0] = ((pr * 0.2f) * 512.0f) * (1.0f / 128.0f);
    out[128 + b * 2 + 1] = ((pc * 0.2f) * 512.0f) * (1.0f / 128.0f);
}

// ---------------------------------------------------------------------------
extern "C" void kernel_launch(void* const* d_in, const int* in_sizes, int n_in,
                              void* d_out, int out_size, void* d_ws, size_t ws_size,
                              hipStream_t stream) {
    const float* grd = (const float*)d_in[0];
    const float* sat = (const float*)d_in[1];
    const int*   unc = (const int*)d_in[2];
    float* out = (float*)d_out;
    float* ws  = (float*)d_ws;

    float* inv     = ws + OFF_INV;
    float* S       = ws + OFF_S;
    float* candv   = ws + OFF_CANDV;
    int*   candi   = (int*)(ws + OFF_CANDI);
    float* dots    = ws + OFF_DOTS;
    float* partial = ws + OFF_PART;
    _Float16* g2   = (_Float16*)(ws + OFF_G2F);
    _Float16* sh   = (_Float16*)(ws + OFF_SH);    // ~15.7 MB total ws use

    hipMemsetAsync(partial, 0, 819200 * sizeof(float), stream);
    hipMemsetAsync(dots, 0, 512 * sizeof(float), stream);
    prep_kernel<<<PREP_BLOCKS, 256, 0, stream>>>(grd, sat, g2, sh, S, inv);
    corr_mfma_kernel<<<dim3(M_SAT, 5, 8), 256, 0, stream>>>(sh, g2, partial);
    epilogue_kernel<<<M_SAT * N_GRD, 256, 0, stream>>>(partial, S, inv, unc, candv, candi);
    refine_dot_kernel<<<dim3(128, 4, 8), 256, 0, stream>>>(grd, sat, candv, candi, dots);
    refine_pick_kernel<<<1, 128, 0, stream>>>(S, inv, unc, candv, candi, dots, out);
}